// Round 1
// baseline (238.834 us; speedup 1.0000x reference)
//
#include <hip/hip_runtime.h>

// VQ-VAE forward: out = code_out[argmax_c(logits_c(x))], hard_idx = argmax.
// logits are piecewise-linear in the scalar input x (128 relu breakpoints),
// so we precompute per-interval affine coefficients (fp64 = exact math) and
// reduce per-sample work to a 512-entry affine argmax scan from LDS.

#define B_SAMPLES 262144
#define HIDDEN    128
#define NUM_CODES 512
#define EMBED_DIM 256
#define NUM_INT   129   // HIDDEN + 1 intervals

// ---- workspace layout (byte offsets) ----
// 0       : t_sorted[128] double            (1 KB)
// 2048    : code_out[512] double            (4 KB)
// 8192    : AB[129*512] double2             (1.03 MB)
// 1064960 : hist[129] int
// 1065984 : bin_start[130] int
// 1067008 : bin_cursor[129] int
// 1068032 : sorted_idx[B] int               (1 MB)  -> total ~2.1 MB

__device__ __forceinline__ int classify(const double* ts, double xv) {
  // first index with ts[idx] > xv; samples exactly on a threshold may go to
  // either side (the relu there contributes exactly 0, logits identical).
  int lo = 0, hi = HIDDEN;
  while (lo < hi) { int mid = (lo + hi) >> 1; if (ts[mid] > xv) hi = mid; else lo = mid + 1; }
  return lo;
}

// P0a: thresholds (sorted), code_out, zero hist. One block.
__global__ void k_prep(const float* __restrict__ w1, const float* __restrict__ b1,
                       const float* __restrict__ emb, const float* __restrict__ decw,
                       const float* __restrict__ decb, double* __restrict__ t_sorted,
                       double* __restrict__ code_out, int* __restrict__ hist) {
  __shared__ double tloc[HIDDEN];
  const int tid = threadIdx.x;
  if (tid < HIDDEN) {
    double w = (double)w1[tid], b = (double)b1[tid];
    double t = -b / w;
    if (!isfinite(t)) t = 1e30;
    t = fmin(fmax(t, -1e30), 1e30);  // keep midpoints finite; |x| << 1e30
    tloc[tid] = t;
  }
  if (tid < NUM_INT) hist[tid] = 0;
  __syncthreads();
  if (tid < HIDDEN) {
    // rank sort (stable for duplicates), O(128^2) total - trivial
    double t = tloc[tid];
    int r = 0;
    for (int k = 0; k < HIDDEN; ++k) {
      double tk = tloc[k];
      r += (tk < t) || (tk == t && k < tid);
    }
    t_sorted[r] = t;
  }
  for (int c = tid; c < NUM_CODES; c += blockDim.x) {
    const float* e = emb + c * EMBED_DIM;
    double s = 0.0;
    for (int d = 0; d < EMBED_DIM; ++d) s = fma((double)e[d], (double)decw[d], s);
    code_out[c] = s + (double)decb[0];
  }
}

// P0b: per-interval affine tables, one block per interval.
__global__ void k_tables(const float* __restrict__ w1, const float* __restrict__ b1,
                         const float* __restrict__ w2, const float* __restrict__ b2,
                         const double* __restrict__ t_sorted, double2* __restrict__ AB) {
  __shared__ double wj[HIDDEN], bj[HIDDEN];
  const int i = blockIdx.x;
  const int tid = threadIdx.x;
  double xm;
  if (i == 0)            xm = t_sorted[0] - 1.0;
  else if (i == HIDDEN)  xm = t_sorted[HIDDEN - 1] + 1.0;
  else                   xm = 0.5 * (t_sorted[i - 1] + t_sorted[i]);
  if (tid < HIDDEN) {
    double w = (double)w1[tid], b = (double)b1[tid];
    bool act = fma(w, xm, b) > 0.0;   // sign constant within the open interval
    wj[tid] = act ? w : 0.0;
    bj[tid] = act ? b : 0.0;
  }
  __syncthreads();
  for (int c = tid; c < NUM_CODES; c += blockDim.x) {
    const float* r = w2 + c * HIDDEN;
    double A = 0.0, Bv = 0.0;
    for (int j = 0; j < HIDDEN; ++j) {
      double v = (double)r[j];
      A  = fma(wj[j], v, A);
      Bv = fma(bj[j], v, Bv);
    }
    Bv += (double)b2[c];
    AB[i * NUM_CODES + c] = make_double2(A, Bv);
  }
}

// P1: classify + histogram. grid = B/256.
__global__ void k_hist(const float* __restrict__ x, const double* __restrict__ t_sorted,
                       int* __restrict__ hist) {
  __shared__ double ts[HIDDEN];
  __shared__ int lh[NUM_INT];
  const int tid = threadIdx.x;
  if (tid < HIDDEN) ts[tid] = t_sorted[tid];
  if (tid < NUM_INT) lh[tid] = 0;
  __syncthreads();
  const int s = blockIdx.x * blockDim.x + tid;
  const int iv = classify(ts, (double)x[s]);
  atomicAdd(&lh[iv], 1);
  __syncthreads();
  if (tid < NUM_INT && lh[tid]) atomicAdd(&hist[tid], lh[tid]);
}

// P2: exclusive prefix over 129 bins (Hillis-Steele in LDS). One block.
__global__ void k_scan(const int* __restrict__ hist, int* __restrict__ bin_start,
                       int* __restrict__ bin_cursor) {
  __shared__ int sh[NUM_INT + 1];
  const int tid = threadIdx.x;
  if (tid <= NUM_INT) sh[tid] = (tid == 0) ? 0 : hist[tid - 1];
  __syncthreads();
  for (int off = 1; off <= NUM_INT; off <<= 1) {
    int v = 0;
    if (tid <= NUM_INT && tid >= off) v = sh[tid - off];
    __syncthreads();
    if (tid <= NUM_INT) sh[tid] += v;
    __syncthreads();
  }
  if (tid <= NUM_INT) bin_start[tid] = sh[tid];
  if (tid <  NUM_INT) bin_cursor[tid] = sh[tid];
}

// P3: block-aggregated counting-sort scatter. grid = B/1024, 4 samples/thread.
__global__ void k_scatter(const float* __restrict__ x, const double* __restrict__ t_sorted,
                          int* __restrict__ bin_cursor, int* __restrict__ sorted_idx) {
  __shared__ double ts[HIDDEN];
  __shared__ int lcount[NUM_INT];
  __shared__ int lbase[NUM_INT];
  const int tid = threadIdx.x;
  if (tid < HIDDEN) ts[tid] = t_sorted[tid];
  if (tid < NUM_INT) lcount[tid] = 0;
  __syncthreads();
  const int base_s = blockIdx.x * 1024;
  int iv[4];
  for (int k = 0; k < 4; ++k) {
    const int s = base_s + k * 256 + tid;
    iv[k] = classify(ts, (double)x[s]);
    atomicAdd(&lcount[iv[k]], 1);
  }
  __syncthreads();
  if (tid < NUM_INT) {
    const int c = lcount[tid];
    lbase[tid] = c ? atomicAdd(&bin_cursor[tid], c) : 0;
    lcount[tid] = 0;   // reuse as local rank counter
  }
  __syncthreads();
  for (int k = 0; k < 4; ++k) {
    const int s = base_s + k * 256 + tid;
    const int r = atomicAdd(&lcount[iv[k]], 1);
    sorted_idx[lbase[iv[k]] + r] = s;
  }
}

// P4: main scan. Blocks own 1024 contiguous sorted positions; runs of one
// interval stage their (A,B) row in LDS; all lanes broadcast-read s_ab[c].
__global__ void __launch_bounds__(256) k_main(const float* __restrict__ x,
                       const int* __restrict__ bin_start,
                       const int* __restrict__ sorted_idx,
                       const double2* __restrict__ AB,
                       const double* __restrict__ code_out,
                       float* __restrict__ out, float* __restrict__ idx_out) {
  __shared__ int sb[NUM_INT + 1];
  __shared__ double2 sab[NUM_CODES];
  const int tid = threadIdx.x;
  if (tid <= NUM_INT) sb[tid] = bin_start[tid];
  __syncthreads();
  const int p0 = blockIdx.x * 1024;
  const int p1 = p0 + 1024;       // B divisible by 1024
  int i = 0;
  int p = p0;
  while (p < p1) {                // p, i, rend are block-uniform
    while (sb[i + 1] <= p) ++i;
    const int rend = min(sb[i + 1], p1);
    __syncthreads();              // protect sab from previous run's readers
    const double2* row = AB + i * NUM_CODES;
    for (int k = tid; k < NUM_CODES; k += 256) sab[k] = row[k];
    __syncthreads();
    for (int q = p + tid; q < rend; q += 256) {
      const int s = sorted_idx[q];
      const double xv = (double)x[s];
      double best = -1e300;
      int bi = 0;
      #pragma unroll 8
      for (int c = 0; c < NUM_CODES; ++c) {
        const double2 ab = sab[c];
        const double v = fma(ab.x, xv, ab.y);
        if (v > best) { best = v; bi = c; }   // strict > == first-max (jnp.argmax)
      }
      out[s]     = (float)code_out[bi];
      idx_out[s] = (float)bi;
    }
    p = rend;
  }
}

extern "C" void kernel_launch(void* const* d_in, const int* in_sizes, int n_in,
                              void* d_out, int out_size, void* d_ws, size_t ws_size,
                              hipStream_t stream) {
  const float* x    = (const float*)d_in[0];
  const float* w1   = (const float*)d_in[1];
  const float* b1   = (const float*)d_in[2];
  const float* w2   = (const float*)d_in[3];
  const float* b2   = (const float*)d_in[4];
  const float* emb  = (const float*)d_in[5];
  const float* decw = (const float*)d_in[6];
  const float* decb = (const float*)d_in[7];

  char* ws = (char*)d_ws;
  double*  t_sorted   = (double*) (ws + 0);
  double*  code_out   = (double*) (ws + 2048);
  double2* AB         = (double2*)(ws + 8192);
  int*     hist       = (int*)    (ws + 1064960);
  int*     bin_start  = (int*)    (ws + 1065984);
  int*     bin_cursor = (int*)    (ws + 1067008);
  int*     sorted_idx = (int*)    (ws + 1068032);

  float* out  = (float*)d_out;
  float* idxo = out + B_SAMPLES;

  k_prep   <<<1,               256, 0, stream>>>(w1, b1, emb, decw, decb, t_sorted, code_out, hist);
  k_tables <<<NUM_INT,         256, 0, stream>>>(w1, b1, w2, b2, t_sorted, AB);
  k_hist   <<<B_SAMPLES/256,   256, 0, stream>>>(x, t_sorted, hist);
  k_scan   <<<1,               256, 0, stream>>>(hist, bin_start, bin_cursor);
  k_scatter<<<B_SAMPLES/1024,  256, 0, stream>>>(x, t_sorted, bin_cursor, sorted_idx);
  k_main   <<<B_SAMPLES/1024,  256, 0, stream>>>(x, bin_start, sorted_idx, AB, code_out, out, idxo);
}

// Round 2
// 212.934 us; speedup vs baseline: 1.1216x; 1.1216x over previous
//
#include <hip/hip_runtime.h>

// VQ-VAE forward: out = code_out[argmax_c(logits_c(x))], hard_idx = argmax.
// logits are piecewise-linear in scalar x (128 relu breakpoints). Per interval
// we build the UPPER ENVELOPE of the 512 affine logit lines (fp64-exact,
// parallel pairwise L/U-bound formulation -- no serial hull), giving a global
// piecewise-constant map x -> (idx, out). Samples then do a 7-step interval
// classify + ~6-step binary search. No sample sort needed at all.

#define B_SAMPLES 262144
#define HIDDEN    128
#define NUM_CODES 512
#define EMBED_DIM 256
#define NUM_INT   129   // HIDDEN + 1 intervals

// ---- workspace layout (byte offsets) ----
// 0       : t_sorted[128] double             (1 KB)
// 2048    : code_out[512] double             (4 KB)
// 8192    : env_cnt[129] int
// 9216    : surv[129*512] uchar              (64.5 KB)
// 75264   : Lx[129*512] double               (516 KB)
// 603648  : AB[129*512] double2              (1.03 MB)
// 1660416 : env_xs[129*512] double           (516 KB)
// 2188800 : env_idx[129*512] int             (258 KB)  -> total ~2.34 MB

__device__ __forceinline__ int classify(const double* ts, double xv) {
  // first index with ts[idx] > xv
  int lo = 0, hi = HIDDEN;
  while (lo < hi) { int mid = (lo + hi) >> 1; if (ts[mid] > xv) hi = mid; else lo = mid + 1; }
  return lo;
}

// P0a: sorted thresholds, code_out, zero env_cnt. One block.
__global__ void k_prep(const float* __restrict__ w1, const float* __restrict__ b1,
                       const float* __restrict__ emb, const float* __restrict__ decw,
                       const float* __restrict__ decb, double* __restrict__ t_sorted,
                       double* __restrict__ code_out, int* __restrict__ env_cnt) {
  __shared__ double tloc[HIDDEN];
  const int tid = threadIdx.x;
  if (tid < HIDDEN) {
    double w = (double)w1[tid], b = (double)b1[tid];
    double t = -b / w;
    if (!isfinite(t)) t = 1e30;
    t = fmin(fmax(t, -1e30), 1e30);
    tloc[tid] = t;
  }
  if (tid < NUM_INT) env_cnt[tid] = 0;
  __syncthreads();
  if (tid < HIDDEN) {
    double t = tloc[tid];
    int r = 0;
    for (int k = 0; k < HIDDEN; ++k) {
      double tk = tloc[k];
      r += (tk < t) || (tk == t && k < tid);
    }
    t_sorted[r] = t;
  }
  for (int c = tid; c < NUM_CODES; c += blockDim.x) {
    const float* e = emb + c * EMBED_DIM;
    double s = 0.0;
    for (int d = 0; d < EMBED_DIM; ++d) s = fma((double)e[d], (double)decw[d], s);
    code_out[c] = s + (double)decb[0];
  }
}

// P0b: per-interval affine coefficients (A,B) per code. One block per interval.
__global__ void k_tables(const float* __restrict__ w1, const float* __restrict__ b1,
                         const float* __restrict__ w2, const float* __restrict__ b2,
                         const double* __restrict__ t_sorted, double2* __restrict__ AB) {
  __shared__ double wj[HIDDEN], bj[HIDDEN];
  const int i = blockIdx.x;
  const int tid = threadIdx.x;
  double xm;
  if (i == 0)            xm = t_sorted[0] - 1.0;
  else if (i == HIDDEN)  xm = t_sorted[HIDDEN - 1] + 1.0;
  else                   xm = 0.5 * (t_sorted[i - 1] + t_sorted[i]);
  if (tid < HIDDEN) {
    double w = (double)w1[tid], b = (double)b1[tid];
    bool act = fma(w, xm, b) > 0.0;   // relu sign constant within open interval
    wj[tid] = act ? w : 0.0;
    bj[tid] = act ? b : 0.0;
  }
  __syncthreads();
  for (int c = tid; c < NUM_CODES; c += blockDim.x) {
    const float* r = w2 + c * HIDDEN;
    double A = 0.0, Bv = 0.0;
    for (int j = 0; j < HIDDEN; ++j) {
      double v = (double)r[j];
      A  = fma(wj[j], v, A);
      Bv = fma(bj[j], v, Bv);
    }
    Bv += (double)b2[c];
    AB[i * NUM_CODES + c] = make_double2(A, Bv);
  }
}

// P1: pairwise envelope membership. Line l survives iff not dominated in its
// equal-slope class and L = max_{A_k<A_l} x*(l,k) < U = min_{A_k>A_l} x*(l,k).
// Fractions kept as (num, den>0) pairs; (-1,0) = -inf, (1,0) = +inf.
// Two threads per (interval,code) split the k-range; merged via shfl_xor(1).
__global__ void __launch_bounds__(256) k_env1(const double2* __restrict__ AB,
                       unsigned char* __restrict__ surv, double* __restrict__ Lx,
                       int* __restrict__ env_cnt) {
  const int gid  = blockIdx.x * 256 + threadIdx.x;
  const int pair = gid >> 1;        // (interval,code)
  const int half = gid & 1;
  const int i = pair >> 9;
  const int c = pair & 511;
  const int base = i << 9;
  const double2 my = AB[base + c];
  double nL0=-1.0,dL0=0.0,nU0=1.0,dU0=0.0; int dead0=0;
  double nL1=-1.0,dL1=0.0,nU1=1.0,dU1=0.0; int dead1=0;
  const int k0 = half << 8;
  #pragma unroll 8
  for (int kk = 0; kk < 256; kk += 2) {
    {
      const int k = k0 + kk;
      const double2 o = AB[base + k];
      const double d = my.x - o.x;    // A_l - A_k
      const double n = o.y - my.y;    // B_k - B_l
      if (d == 0.0) {
        dead0 |= (n > 0.0) || (n == 0.0 && k < c);   // first-index tie rule
      } else if (d > 0.0) {           // k lower slope: lower bound cand n/d
        if (n * dL0 > nL0 * d) { nL0 = n; dL0 = d; }
      } else {                        // k higher slope: upper bound cand (-n)/(-d)
        if ((-n) * dU0 < nU0 * (-d)) { nU0 = -n; dU0 = -d; }
      }
    }
    {
      const int k = k0 + kk + 1;
      const double2 o = AB[base + k];
      const double d = my.x - o.x;
      const double n = o.y - my.y;
      if (d == 0.0) {
        dead1 |= (n > 0.0) || (n == 0.0 && k < c);
      } else if (d > 0.0) {
        if (n * dL1 > nL1 * d) { nL1 = n; dL1 = d; }
      } else {
        if ((-n) * dU1 < nU1 * (-d)) { nU1 = -n; dU1 = -d; }
      }
    }
  }
  // merge accumulator set 1 into 0
  if (nL1 * dL0 > nL0 * dL1) { nL0 = nL1; dL0 = dL1; }
  if (nU1 * dU0 < nU0 * dU1) { nU0 = nU1; dU0 = dU1; }
  dead0 |= dead1;
  // merge across the shuffle pair
  const double onL = __shfl_xor(nL0, 1), odL = __shfl_xor(dL0, 1);
  const double onU = __shfl_xor(nU0, 1), odU = __shfl_xor(dU0, 1);
  const int odead = __shfl_xor(dead0, 1);
  if (onL * dL0 > nL0 * odL) { nL0 = onL; dL0 = odL; }
  if (onU * dU0 < nU0 * odU) { nU0 = onU; dU0 = odU; }
  dead0 |= odead;
  if (half == 0) {
    const int sv = (!dead0) && (dL0 == 0.0 || dU0 == 0.0 || nL0 * dU0 < nU0 * dL0);
    surv[pair] = (unsigned char)sv;
    Lx[pair]   = (dL0 == 0.0) ? -1e300 : nL0 / dL0;
    if (sv) atomicAdd(&env_cnt[i], 1);
  }
}

// P2: compact survivors into per-interval sorted segment tables.
// rank = #survivors with smaller slope (survivor slopes are distinct).
__global__ void __launch_bounds__(256) k_env2(const double2* __restrict__ AB,
                       const unsigned char* __restrict__ surv,
                       const double* __restrict__ Lx,
                       double* __restrict__ env_xs, int* __restrict__ env_idx) {
  const int pair = blockIdx.x * 256 + threadIdx.x;
  const int i = pair >> 9;
  const int base = i << 9;
  const double myA = AB[pair].x;
  int rank = 0;
  #pragma unroll 4
  for (int k = 0; k < NUM_CODES; ++k) {
    rank += (surv[base + k] && (AB[base + k].x < myA)) ? 1 : 0;
  }
  if (surv[pair]) {
    env_xs[base + rank]  = Lx[pair];
    env_idx[base + rank] = pair & 511;
  }
}

// P3: per-sample lookup: classify interval (LDS), binary search segment starts.
__global__ void __launch_bounds__(256) k_map(const float* __restrict__ x,
                       const double* __restrict__ t_sorted,
                       const int* __restrict__ env_cnt,
                       const double* __restrict__ env_xs,
                       const int* __restrict__ env_idx,
                       const double* __restrict__ code_out,
                       float* __restrict__ out, float* __restrict__ idx_out) {
  __shared__ double ts[HIDDEN];
  const int tid = threadIdx.x;
  if (tid < HIDDEN) ts[tid] = t_sorted[tid];
  __syncthreads();
  const int s = blockIdx.x * 256 + tid;
  const double xv = (double)x[s];
  const int i = classify(ts, xv);
  const int base = i << 9;
  const int cnt = env_cnt[i];
  int lo = 0, hi = cnt - 1;
  while (lo < hi) {                       // find largest j with xs[j] <= xv
    const int mid = (lo + hi + 1) >> 1;
    if (env_xs[base + mid] <= xv) lo = mid; else hi = mid - 1;
  }
  const int ci = env_idx[base + lo];
  out[s]     = (float)code_out[ci];
  idx_out[s] = (float)ci;
}

extern "C" void kernel_launch(void* const* d_in, const int* in_sizes, int n_in,
                              void* d_out, int out_size, void* d_ws, size_t ws_size,
                              hipStream_t stream) {
  const float* x    = (const float*)d_in[0];
  const float* w1   = (const float*)d_in[1];
  const float* b1   = (const float*)d_in[2];
  const float* w2   = (const float*)d_in[3];
  const float* b2   = (const float*)d_in[4];
  const float* emb  = (const float*)d_in[5];
  const float* decw = (const float*)d_in[6];
  const float* decb = (const float*)d_in[7];

  char* ws = (char*)d_ws;
  double*        t_sorted = (double*)        (ws + 0);
  double*        code_out = (double*)        (ws + 2048);
  int*           env_cnt  = (int*)           (ws + 8192);
  unsigned char* surv     = (unsigned char*) (ws + 9216);
  double*        Lx       = (double*)        (ws + 75264);
  double2*       AB       = (double2*)       (ws + 603648);
  double*        env_xs   = (double*)        (ws + 1660416);
  int*           env_idx  = (int*)           (ws + 2188800);

  float* out  = (float*)d_out;
  float* idxo = out + B_SAMPLES;

  k_prep  <<<1,                         256, 0, stream>>>(w1, b1, emb, decw, decb, t_sorted, code_out, env_cnt);
  k_tables<<<NUM_INT,                   256, 0, stream>>>(w1, b1, w2, b2, t_sorted, AB);
  k_env1  <<<NUM_INT * NUM_CODES / 128, 256, 0, stream>>>(AB, surv, Lx, env_cnt);
  k_env2  <<<NUM_INT * NUM_CODES / 256, 256, 0, stream>>>(AB, surv, Lx, env_xs, env_idx);
  k_map   <<<B_SAMPLES / 256,           256, 0, stream>>>(x, t_sorted, env_cnt, env_xs, env_idx, code_out, out, idxo);
}